// Round 5
// baseline (117.565 us; speedup 1.0000x reference)
//
#include <hip/hip_runtime.h>

#define HGT 1024
#define WID 1024
#define NB 8
#define NPIX ((size_t)NB * HGT * WID)

// ---------------------------------------------------------------------------
// Global interval-bound reduction: maxT, maxSlow=max(1/sos), badness flags.
// atomicMax on nonneg-float bits is order-isomorphic -> deterministic.
// fl[0]=maxT bits, fl[1]=maxSlow bits, fl[2]=bad (negatives/NaN present).
// ---------------------------------------------------------------------------
__global__ __launch_bounds__(256)
void reduce_kernel(const float* __restrict__ T, const float* __restrict__ sos,
                   unsigned* __restrict__ fl) {
    float mT = 0.0f, mS = 0.0f;
    unsigned bad = 0u;
    const float4* T4 = (const float4*)T;
    const float4* S4 = (const float4*)sos;
    const size_t n4 = NPIX / 4;
    for (size_t i = (size_t)blockIdx.x * blockDim.x + threadIdx.x; i < n4;
         i += (size_t)gridDim.x * blockDim.x) {
        const float4 t = T4[i], s = S4[i];
        // !(x>=0) catches negatives AND NaN
        bad |= (!(t.x >= 0.f)) | (!(t.y >= 0.f)) | (!(t.z >= 0.f)) | (!(t.w >= 0.f));
        bad |= (!(s.x >= 0.f)) | (!(s.y >= 0.f)) | (!(s.z >= 0.f)) | (!(s.w >= 0.f));
        mT = fmaxf(mT, fmaxf(fmaxf(t.x, t.y), fmaxf(t.z, t.w)));
        const float r0 = 1.0f / s.x, r1 = 1.0f / s.y, r2 = 1.0f / s.z, r3 = 1.0f / s.w;
        mS = fmaxf(mS, fmaxf(fmaxf(r0, r1), fmaxf(r2, r3)));  // sos=+0 -> +inf -> bound fails
    }
    __shared__ float sT[256], sS[256];
    __shared__ unsigned sB[256];
    const int tid = threadIdx.x;
    sT[tid] = mT; sS[tid] = mS; sB[tid] = bad;
    __syncthreads();
    for (int st = 128; st > 0; st >>= 1) {
        if (tid < st) {
            sT[tid] = fmaxf(sT[tid], sT[tid + st]);
            sS[tid] = fmaxf(sS[tid], sS[tid + st]);
            sB[tid] |= sB[tid + st];
        }
        __syncthreads();
    }
    if (tid == 0) {
        atomicMax(&fl[0], __float_as_uint(sT[0]));  // nonneg floats: bits monotonic
        atomicMax(&fl[1], __float_as_uint(sS[0]));
        atomicOr(&fl[2], sB[0]);
    }
}

// Rigorous underflow bound over layers [l0, l0+nl):
//   T_final <= maxT * prod_l( (sum of taps_l) * maxSlow ) * (1+eps)^~200
// computed in log2 space; returns true only when the true result must round
// to exactly +0 in fp32 (threshold -151 vs the -150 round-to-zero cutoff,
// leaving >0.9 bits for log2f error and op-rounding slack). NaN-safe
// (NaN < x is false), requires nonneg taps and clean (nonneg, non-NaN) data.
__device__ __forceinline__ bool zero_bound(const unsigned* fl, const float* wts,
                                           int l0, int nl) {
    if (!fl) return false;
    if (fl[2] != 0u) return false;
    const float maxT = __uint_as_float(fl[0]);
    const float maxSlow = __uint_as_float(fl[1]);
    float lb = log2f(maxT);
    for (int l = l0; l < l0 + nl; ++l) {
        float s = 0.0f;
        bool ok = true;
        #pragma unroll
        for (int k = 0; k < 9; ++k) {
            const float w = wts[l * 9 + k];
            ok &= (w >= 0.0f);
            s += w;
        }
        if (!ok) return false;
        lb += log2f(s * maxSlow);
    }
    return lb < -151.0f;
}

// ---------------------------------------------------------------------------
// Fused NITER-layer eikonal sweep (round-3-proven body, VGPR~60 no-spill)
// + global zero-bound shortcut + per-tile all-zero early exit.
//
// Exactness notes:
//  - zero outer ring + zero OOI cells emulate SAME zero padding exactly;
//  - T>=0, w>0 => min(0, acc*slow)=0, so OOI cells self-preserve (no mask);
//  - halo=NITER => inner 64x64 exact after NITER iters (trapezoid rule);
//  - zero_bound true => every output underflows to +0 (rigorous, any input);
//  - all-zero loaded tile is a fixed point for ANY weights => write zeros;
//  - uniform-weight box-sum path: rounding differs from the reference FMA
//    chain but the state underflows to +0 before reaching the output;
//  - general path: FMA chain identical to the validated round-1 kernel.
// ---------------------------------------------------------------------------
template <int NITER>
__global__ __launch_bounds__(256, 4)
void eik_fused(const float* __restrict__ Tin, const float* __restrict__ sos,
               const float* __restrict__ wts, int layer0, float* __restrict__ Tout,
               const unsigned* __restrict__ fl, int bl0, int bnl) {
    constexpr int TILE = 64;
    constexpr int HALO = NITER;              // 8
    constexpr int P = TILE + 2 * HALO;       // 80
    constexpr int CW = 5, CH = 5;
    constexpr int LSTR = 81;
    constexpr int LROWS = P + 3;             // 83 (covers col-81 alias reads)

    __shared__ float lds[LROWS * LSTR];

    const int tid = threadIdx.x;
    const int tx = tid & 15, ty = tid >> 4;
    const int gx0 = blockIdx.x * TILE - HALO;
    const int gy0 = blockIdx.y * TILE - HALO;
    const size_t base = (size_t)blockIdx.z * HGT * WID;

    // global underflow shortcut: stream zeros, skip everything
    if (zero_bound(fl, wts, bl0, bnl)) {
        for (int i = tid; i < TILE * (TILE / 4); i += 256) {
            const int r = i >> 4, q = i & 15;
            *reinterpret_cast<float4*>(
                &Tout[base + (size_t)(gy0 + HALO + r) * WID + (gx0 + HALO + 4 * q)]) =
                make_float4(0.f, 0.f, 0.f, 0.f);
        }
        return;
    }

    // zero all of LDS (outer ring + out-of-image cells)
    for (int i = tid; i < LROWS * LSTR; i += 256) lds[i] = 0.0f;
    __syncthreads();

    // cooperative tile load (scalar, proven conflict-light), tracking nonzero
    unsigned nz = 0u;
    for (int i = tid; i < P * P; i += 256) {
        const int r = i / P, c = i % P;
        const int gy = gy0 + r, gx = gx0 + c;
        float v = 0.0f;
        if (gy >= 0 && gy < HGT && gx >= 0 && gx < WID)
            v = Tin[base + (size_t)gy * WID + gx];
        nz |= __float_as_uint(v);
        lds[(r + 1) * LSTR + (c + 1)] = v;
    }

    if (__syncthreads_and(nz == 0u)) {
        // zero tile is a fixed point: output zeros, skip sos + iterations
        for (int i = tid; i < TILE * (TILE / 4); i += 256) {
            const int r = i >> 4, q = i & 15;
            *reinterpret_cast<float4*>(
                &Tout[base + (size_t)(gy0 + HALO + r) * WID + (gx0 + HALO + 4 * q)]) =
                make_float4(0.f, 0.f, 0.f, 0.f);
        }
        return;
    }

    // per-thread slowness for owned cells (registers; 25 regs, round-3-proven)
    const int R0 = ty * CH, C0 = tx * CW;
    float slow[CH][CW];
    #pragma unroll
    for (int r = 0; r < CH; ++r) {
        #pragma unroll
        for (int j = 0; j < CW; ++j) {
            const int gy = gy0 + R0 + r, gx = gx0 + C0 + j;
            float sv = 1.0f;
            if (gy >= 0 && gy < HGT && gx >= 0 && gx < WID)
                sv = sos[base + (size_t)gy * WID + gx];
            slow[r][j] = 1.0f / sv;
        }
    }

    float nw[CH][CW];
    #pragma unroll 1
    for (int it = 0; it < NITER; ++it) {
        const float* __restrict__ w = wts + (size_t)(layer0 + it) * 9;
        const float w00 = w[0], w01 = w[1], w02 = w[2];
        const float w10 = w[3], w11 = w[4], w12 = w[5];
        const float w20 = w[6], w21 = w[7], w22 = w[8];

        const bool uni = (w00 == w01) & (w01 == w02) & (w02 == w10) &
                         (w10 == w11) & (w11 == w12) & (w12 == w20) &
                         (w20 == w21) & (w21 == w22);

        float a[CW + 2], bb[CW + 2], cc[CW + 2];
        #pragma unroll
        for (int k = 0; k < CW + 2; ++k) a[k] = lds[R0 * LSTR + C0 + k];
        #pragma unroll
        for (int k = 0; k < CW + 2; ++k) bb[k] = lds[(R0 + 1) * LSTR + C0 + k];

        if (uni) {
            const float wu = w00;
            #pragma unroll
            for (int r = 0; r < CH; ++r) {
                #pragma unroll
                for (int k = 0; k < CW + 2; ++k) cc[k] = lds[(R0 + r + 2) * LSTR + C0 + k];
                float cs[CW + 2];
                #pragma unroll
                for (int k = 0; k < CW + 2; ++k) cs[k] = a[k] + bb[k] + cc[k];
                #pragma unroll
                for (int j = 0; j < CW; ++j) {
                    const float s9 = cs[j] + cs[j + 1] + cs[j + 2];
                    nw[r][j] = fminf(bb[j + 1], s9 * wu * slow[r][j]);
                }
                #pragma unroll
                for (int k = 0; k < CW + 2; ++k) { a[k] = bb[k]; bb[k] = cc[k]; }
            }
        } else {
            // exact general path (round-1-identical FMA chain)
            #pragma unroll
            for (int r = 0; r < CH; ++r) {
                #pragma unroll
                for (int k = 0; k < CW + 2; ++k) cc[k] = lds[(R0 + r + 2) * LSTR + C0 + k];
                #pragma unroll
                for (int j = 0; j < CW; ++j) {
                    float acc = a[j] * w00 + a[j + 1] * w01 + a[j + 2] * w02
                              + bb[j] * w10 + bb[j + 1] * w11 + bb[j + 2] * w12
                              + cc[j] * w20 + cc[j + 1] * w21 + cc[j + 2] * w22;
                    nw[r][j] = fminf(bb[j + 1], acc * slow[r][j]);
                }
                #pragma unroll
                for (int k = 0; k < CW + 2; ++k) { a[k] = bb[k]; bb[k] = cc[k]; }
            }
        }
        __syncthreads();
        #pragma unroll
        for (int r = 0; r < CH; ++r)
            #pragma unroll
            for (int j = 0; j < CW; ++j)
                lds[(R0 + r + 1) * LSTR + C0 + j + 1] = nw[r][j];
        __syncthreads();
    }

    // vectorized write of valid inner TILE x TILE (always fully in-image)
    for (int i = tid; i < TILE * (TILE / 4); i += 256) {
        const int r = i >> 4, q = i & 15;
        const int o = (HALO + r + 1) * LSTR + HALO + 4 * q + 1;
        float4 v;
        v.x = lds[o]; v.y = lds[o + 1]; v.z = lds[o + 2]; v.w = lds[o + 3];
        *reinterpret_cast<float4*>(
            &Tout[base + (size_t)(gy0 + HALO + r) * WID + (gx0 + HALO + 4 * q)]) = v;
    }
}

extern "C" void kernel_launch(void* const* d_in, const int* in_sizes, int n_in,
                              void* d_out, int out_size, void* d_ws, size_t ws_size,
                              hipStream_t stream) {
    const float* T_init = (const float*)d_in[0];
    const float* sos    = (const float*)d_in[1];
    const float* wts    = (const float*)d_in[2];
    float* out = (float*)d_out;
    float* mid = (float*)d_ws;                 // 32 MB intermediate
    const size_t bytes = NPIX * sizeof(float);

    unsigned* fl = nullptr;
    if (ws_size >= bytes + 64) {
        fl = (unsigned*)((char*)d_ws + bytes);
        hipMemsetAsync(fl, 0, 3 * sizeof(unsigned), stream);
        reduce_kernel<<<dim3(2048), dim3(256), 0, stream>>>(T_init, sos, fl);
    }

    const dim3 blk(256, 1, 1);
    const dim3 grd(WID / 64, HGT / 64, NB);    // 16 x 16 x 8 = 2048 blocks

    // pass 1: layers 0..7 (bound over layers 0..7); pass 2: layers 8..15
    // (bound over the full 0..15 chain from T_init).
    eik_fused<8><<<grd, blk, 0, stream>>>(T_init, sos, wts, 0, mid, fl, 0, 8);
    eik_fused<8><<<grd, blk, 0, stream>>>(mid,    sos, wts, 8, out, fl, 0, 16);
}

// Round 6
// 36.126 us; speedup vs baseline: 3.2543x; 3.2543x over previous
//
#include <hip/hip_runtime.h>

#define HGT 1024
#define WID 1024
#define NB 8
#define NPIX ((size_t)NB * HGT * WID)
#define RBLKS 1024

// ---------------------------------------------------------------------------
// Stage 1: per-block {maxT, minSos, bad} partials. No atomics, no contention.
// Exactly 8 iterations per thread (1024 blk x 256 th x 8 x float4 == NPIX).
// ---------------------------------------------------------------------------
__global__ __launch_bounds__(256)
void reduce_minmax(const float* __restrict__ T, const float* __restrict__ sos,
                   uint4* __restrict__ partials) {
    const float4* T4 = (const float4*)T;
    const float4* S4 = (const float4*)sos;
    float mT = 0.0f, mS = __builtin_huge_valf();
    unsigned bad = 0u;
    const size_t i0 = (size_t)blockIdx.x * 256 + threadIdx.x;
    #pragma unroll
    for (int k = 0; k < 8; ++k) {
        const size_t i = i0 + (size_t)k * (RBLKS * 256);
        const float4 t = T4[i], s = S4[i];
        // !(x>=0) catches negatives AND NaN
        bad |= (!(t.x >= 0.f)) | (!(t.y >= 0.f)) | (!(t.z >= 0.f)) | (!(t.w >= 0.f));
        bad |= (!(s.x >= 0.f)) | (!(s.y >= 0.f)) | (!(s.z >= 0.f)) | (!(s.w >= 0.f));
        mT = fmaxf(mT, fmaxf(fmaxf(t.x, t.y), fmaxf(t.z, t.w)));
        mS = fminf(mS, fminf(fminf(s.x, s.y), fminf(s.z, s.w)));
    }
    __shared__ float sT[256], sS[256];
    __shared__ unsigned sB[256];
    const int tid = threadIdx.x;
    sT[tid] = mT; sS[tid] = mS; sB[tid] = bad;
    __syncthreads();
    for (int st = 128; st > 0; st >>= 1) {
        if (tid < st) {
            sT[tid] = fmaxf(sT[tid], sT[tid + st]);
            sS[tid] = fminf(sS[tid], sS[tid + st]);
            sB[tid] |= sB[tid + st];
        }
        __syncthreads();
    }
    if (tid == 0)
        partials[blockIdx.x] =
            make_uint4(__float_as_uint(sT[0]), __float_as_uint(sS[0]), sB[0], 0u);
}

// ---------------------------------------------------------------------------
// Stage 2: fold partials, evaluate the rigorous underflow bound, publish flags.
//   bit0: output of layers [0,8)  from T_init must round to exactly +0
//   bit1: output of layers [0,16) from T_init must round to exactly +0
// Bound: T_l <= maxT * prod(sum_taps_l * maxSlow), in log2 space, with
// maxSlow = rn(1/min sos) (monotone rounding => exact max of per-elem rn(1/s)).
// Threshold -151 vs the -150 round-to-zero cutoff leaves margin for log2f
// error and op roundings. NaN/negative data or taps disable the bound.
// Note min(T,0)=0 for T>=0 and conv(0)=0, so once a layer's product chain
// underflows, zero persists through all remaining layers -> requiring the
// FULL-range bound (not just a prefix) is strictly conservative.
// ---------------------------------------------------------------------------
__global__ __launch_bounds__(256)
void finalize_bound(const uint4* __restrict__ partials,
                    const float* __restrict__ wts, unsigned* __restrict__ fl2) {
    const int tid = threadIdx.x;
    float mT = 0.0f, mS = __builtin_huge_valf();
    unsigned bad = 0u;
    #pragma unroll
    for (int k = 0; k < RBLKS / 256; ++k) {
        const uint4 p = partials[tid + k * 256];
        mT = fmaxf(mT, __uint_as_float(p.x));
        mS = fminf(mS, __uint_as_float(p.y));
        bad |= p.z;
    }
    __shared__ float sT[256], sS[256];
    __shared__ unsigned sB[256];
    sT[tid] = mT; sS[tid] = mS; sB[tid] = bad;
    __syncthreads();
    for (int st = 128; st > 0; st >>= 1) {
        if (tid < st) {
            sT[tid] = fmaxf(sT[tid], sT[tid + st]);
            sS[tid] = fminf(sS[tid], sS[tid + st]);
            sB[tid] |= sB[tid + st];
        }
        __syncthreads();
    }
    if (tid == 0) {
        unsigned bits = 0u;
        if (sB[0] == 0u) {
            const float maxSlow = 1.0f / sS[0];
            float lb = log2f(sT[0]);
            bool ok = true;
            for (int l = 0; l < 16 && ok; ++l) {
                float s = 0.0f;
                #pragma unroll
                for (int k = 0; k < 9; ++k) {
                    const float w = wts[l * 9 + k];
                    ok &= (w >= 0.0f);
                    s += w;
                }
                if (!ok) break;
                lb += log2f(s * maxSlow);
                if (l == 7 && lb < -151.0f) bits |= 1u;
            }
            if (ok && lb < -151.0f) bits |= 2u;
        }
        fl2[0] = bits;
    }
}

// ---------------------------------------------------------------------------
// Fused NITER-layer eikonal sweep (round-3-proven body, VGPR~60 no-spill)
// + flag-driven skip/zero shortcuts + per-tile all-zero early exit.
//
// Exactness notes:
//  - zero outer ring + zero OOI cells emulate SAME zero padding exactly;
//  - T>=0, w>0 => min(0, acc*slow)=0, so OOI cells self-preserve (no mask);
//  - halo=NITER => inner 64x64 exact after NITER iters (trapezoid rule);
//  - skipmask hit => this pass's output is never read downstream: write nothing;
//  - zeromask hit => every output underflows to +0 (rigorous, any input);
//  - all-zero loaded tile is a fixed point for ANY weights => write zeros;
//  - uniform-weight box-sum path: rounding differs from the reference FMA
//    chain but the state underflows to +0 before reaching the output;
//  - general path: FMA chain identical to the validated round-1 kernel.
// ---------------------------------------------------------------------------
template <int NITER>
__global__ __launch_bounds__(256, 4)
void eik_fused(const float* __restrict__ Tin, const float* __restrict__ sos,
               const float* __restrict__ wts, int layer0, float* __restrict__ Tout,
               const unsigned* __restrict__ fl2, unsigned skipmask, unsigned zeromask) {
    constexpr int TILE = 64;
    constexpr int HALO = NITER;              // 8
    constexpr int P = TILE + 2 * HALO;       // 80
    constexpr int CW = 5, CH = 5;
    constexpr int LSTR = 81;
    constexpr int LROWS = P + 3;             // 83 (covers col-81 alias reads)

    __shared__ float lds[LROWS * LSTR];

    const int tid = threadIdx.x;
    const int tx = tid & 15, ty = tid >> 4;
    const int gx0 = blockIdx.x * TILE - HALO;
    const int gy0 = blockIdx.y * TILE - HALO;
    const size_t base = (size_t)blockIdx.z * HGT * WID;

    const unsigned flags = fl2 ? fl2[0] : 0u;
    if (flags & skipmask) return;  // output never consumed downstream
    if (flags & zeromask) {
        for (int i = tid; i < TILE * (TILE / 4); i += 256) {
            const int r = i >> 4, q = i & 15;
            *reinterpret_cast<float4*>(
                &Tout[base + (size_t)(gy0 + HALO + r) * WID + (gx0 + HALO + 4 * q)]) =
                make_float4(0.f, 0.f, 0.f, 0.f);
        }
        return;
    }

    // zero all of LDS (outer ring + out-of-image cells)
    for (int i = tid; i < LROWS * LSTR; i += 256) lds[i] = 0.0f;
    __syncthreads();

    // cooperative tile load (scalar, proven conflict-light), tracking nonzero
    unsigned nz = 0u;
    for (int i = tid; i < P * P; i += 256) {
        const int r = i / P, c = i % P;
        const int gy = gy0 + r, gx = gx0 + c;
        float v = 0.0f;
        if (gy >= 0 && gy < HGT && gx >= 0 && gx < WID)
            v = Tin[base + (size_t)gy * WID + gx];
        nz |= __float_as_uint(v);
        lds[(r + 1) * LSTR + (c + 1)] = v;
    }

    if (__syncthreads_and(nz == 0u)) {
        // zero tile is a fixed point: output zeros, skip sos + iterations
        for (int i = tid; i < TILE * (TILE / 4); i += 256) {
            const int r = i >> 4, q = i & 15;
            *reinterpret_cast<float4*>(
                &Tout[base + (size_t)(gy0 + HALO + r) * WID + (gx0 + HALO + 4 * q)]) =
                make_float4(0.f, 0.f, 0.f, 0.f);
        }
        return;
    }

    // per-thread slowness for owned cells (registers; 25 regs, round-3-proven)
    const int R0 = ty * CH, C0 = tx * CW;
    float slow[CH][CW];
    #pragma unroll
    for (int r = 0; r < CH; ++r) {
        #pragma unroll
        for (int j = 0; j < CW; ++j) {
            const int gy = gy0 + R0 + r, gx = gx0 + C0 + j;
            float sv = 1.0f;
            if (gy >= 0 && gy < HGT && gx >= 0 && gx < WID)
                sv = sos[base + (size_t)gy * WID + gx];
            slow[r][j] = 1.0f / sv;
        }
    }

    float nw[CH][CW];
    #pragma unroll 1
    for (int it = 0; it < NITER; ++it) {
        const float* __restrict__ w = wts + (size_t)(layer0 + it) * 9;
        const float w00 = w[0], w01 = w[1], w02 = w[2];
        const float w10 = w[3], w11 = w[4], w12 = w[5];
        const float w20 = w[6], w21 = w[7], w22 = w[8];

        const bool uni = (w00 == w01) & (w01 == w02) & (w02 == w10) &
                         (w10 == w11) & (w11 == w12) & (w12 == w20) &
                         (w20 == w21) & (w21 == w22);

        float a[CW + 2], bb[CW + 2], cc[CW + 2];
        #pragma unroll
        for (int k = 0; k < CW + 2; ++k) a[k] = lds[R0 * LSTR + C0 + k];
        #pragma unroll
        for (int k = 0; k < CW + 2; ++k) bb[k] = lds[(R0 + 1) * LSTR + C0 + k];

        if (uni) {
            const float wu = w00;
            #pragma unroll
            for (int r = 0; r < CH; ++r) {
                #pragma unroll
                for (int k = 0; k < CW + 2; ++k) cc[k] = lds[(R0 + r + 2) * LSTR + C0 + k];
                float cs[CW + 2];
                #pragma unroll
                for (int k = 0; k < CW + 2; ++k) cs[k] = a[k] + bb[k] + cc[k];
                #pragma unroll
                for (int j = 0; j < CW; ++j) {
                    const float s9 = cs[j] + cs[j + 1] + cs[j + 2];
                    nw[r][j] = fminf(bb[j + 1], s9 * wu * slow[r][j]);
                }
                #pragma unroll
                for (int k = 0; k < CW + 2; ++k) { a[k] = bb[k]; bb[k] = cc[k]; }
            }
        } else {
            // exact general path (round-1-identical FMA chain)
            #pragma unroll
            for (int r = 0; r < CH; ++r) {
                #pragma unroll
                for (int k = 0; k < CW + 2; ++k) cc[k] = lds[(R0 + r + 2) * LSTR + C0 + k];
                #pragma unroll
                for (int j = 0; j < CW; ++j) {
                    float acc = a[j] * w00 + a[j + 1] * w01 + a[j + 2] * w02
                              + bb[j] * w10 + bb[j + 1] * w11 + bb[j + 2] * w12
                              + cc[j] * w20 + cc[j + 1] * w21 + cc[j + 2] * w22;
                    nw[r][j] = fminf(bb[j + 1], acc * slow[r][j]);
                }
                #pragma unroll
                for (int k = 0; k < CW + 2; ++k) { a[k] = bb[k]; bb[k] = cc[k]; }
            }
        }
        __syncthreads();
        #pragma unroll
        for (int r = 0; r < CH; ++r)
            #pragma unroll
            for (int j = 0; j < CW; ++j)
                lds[(R0 + r + 1) * LSTR + C0 + j + 1] = nw[r][j];
        __syncthreads();
    }

    // vectorized write of valid inner TILE x TILE (always fully in-image)
    for (int i = tid; i < TILE * (TILE / 4); i += 256) {
        const int r = i >> 4, q = i & 15;
        const int o = (HALO + r + 1) * LSTR + HALO + 4 * q + 1;
        float4 v;
        v.x = lds[o]; v.y = lds[o + 1]; v.z = lds[o + 2]; v.w = lds[o + 3];
        *reinterpret_cast<float4*>(
            &Tout[base + (size_t)(gy0 + HALO + r) * WID + (gx0 + HALO + 4 * q)]) = v;
    }
}

extern "C" void kernel_launch(void* const* d_in, const int* in_sizes, int n_in,
                              void* d_out, int out_size, void* d_ws, size_t ws_size,
                              hipStream_t stream) {
    const float* T_init = (const float*)d_in[0];
    const float* sos    = (const float*)d_in[1];
    const float* wts    = (const float*)d_in[2];
    float* out = (float*)d_out;
    float* mid = (float*)d_ws;                 // 32 MB intermediate
    const size_t bytes = NPIX * sizeof(float);

    const dim3 blk(256, 1, 1);
    const dim3 grd(WID / 64, HGT / 64, NB);    // 16 x 16 x 8 = 2048 blocks

    unsigned* fl2 = nullptr;
    if (ws_size >= bytes + 64) {
        // partials live in the FIRST 16 KB of the mid region: consumed by
        // finalize_bound before any pass can overwrite mid. fl2 sits in the
        // proven 64-byte slack past the 32 MB mark.
        uint4* partials = (uint4*)d_ws;
        fl2 = (unsigned*)((char*)d_ws + bytes);
        reduce_minmax<<<dim3(RBLKS), blk, 0, stream>>>(T_init, sos, partials);
        finalize_bound<<<dim3(1), blk, 0, stream>>>(partials, wts, fl2);
    }

    // pass 1: layers 0..7. skip if full-chain bound (bit1) holds (its output
    // is then never read); zero-fill if the 8-layer bound (bit0) holds.
    // pass 2: layers 8..15. zero-fill if full-chain bound (bit1) holds.
    eik_fused<8><<<grd, blk, 0, stream>>>(T_init, sos, wts, 0, mid, fl2, 2u, 1u);
    eik_fused<8><<<grd, blk, 0, stream>>>(mid,    sos, wts, 8, out, fl2, 0u, 2u);
}

// Round 7
// 35.894 us; speedup vs baseline: 3.2754x; 1.0065x over previous
//
#include <hip/hip_runtime.h>

#define HGT 1024
#define WID 1024
#define NB 8
#define NLAY 16

// ---------------------------------------------------------------------------
// Single-dispatch 16-layer eikonal sweep.
//
// Per 64x64 output tile (halo 16 -> 96x96 influence region):
//  phase A: stream T/sos over the 96x96 region (float4), reduce
//           {maxT, minSos, bad(neg/NaN)} block-wide.
//  bound:   T_out <= maxT * prod_l(sum_taps_l * maxSlow), maxSlow=rn(1/minSos)
//           (rn monotone => >= every per-elem rn(1/sos)). Evaluated in log2
//           space; threshold -151 vs fp32's -150 round-to-zero cutoff leaves
//           ~1 bit for log2f error + ~210 op-rounding eps (needs ~3e-5).
//           All influence lies in-tile: values at radius <=16, slowness
//           applied at radius <=15, both within the 96x96 region.
//  holds -> write 64x64 zeros, done (exact: true results round to +0).
//  fails -> 16-iteration fused stencil in LDS (halo=16: 1 cell/iter stale
//           contamination => inner 64x64 exact; zero ring + zero OOI cells
//           reproduce SAME zero padding; T>=0, w>0 => min(0,..)=0 preserves
//           OOI zeros). General path = round-1-validated FMA chain; uniform-
//           weight box-sum path as in round 3.
//
// XCD swizzle: physical block b -> logical tile (b&7)*256 + (b>>3), so each
// XCD owns one batch image; halo re-reads hit that XCD's L2.
// No workspace, no atomics, deterministic (per-tile decisions are pure
// functions of tile data).
// ---------------------------------------------------------------------------
__global__ __launch_bounds__(256)
void eik_all(const float* __restrict__ Tin, const float* __restrict__ sos,
             const float* __restrict__ wts, float* __restrict__ Tout) {
    constexpr int TILE = 64, HALO = 16, P = 96;   // P = TILE + 2*HALO
    constexpr int LSTR = 99, LROWS = 98;          // +1 zero ring each side
    constexpr int CW = 6, CH = 6;                 // 96/16

    __shared__ float lds[LROWS * LSTR];           // 38.8 KB (fallback only)
    __shared__ float swt[NLAY * 9];
    __shared__ float redT[4], redS[4];
    __shared__ unsigned redB[4];
    __shared__ unsigned decision;

    const int tid = threadIdx.x;

    // XCD-chunked swizzle (grid = 2048 = 8 XCDs x 256 tiles = one image each)
    const unsigned bphys = blockIdx.x;
    const unsigned Lt = (bphys & 7u) * 256u + (bphys >> 3u);
    const int bx = Lt & 15, by = (Lt >> 4) & 15, bz = Lt >> 8;
    const int gx0 = bx * TILE - HALO, gy0 = by * TILE - HALO;
    const size_t base = (size_t)bz * HGT * WID;

    if (tid < NLAY * 9) swt[tid] = wts[tid];      // parallel weight stage

    // ---- phase A: stream + reduce (no LDS staging; fallback re-reads L2-hot)
    float mT = 0.0f, mS = __builtin_huge_valf();
    unsigned bad = 0u;
    for (int i = tid; i < P * (P / 4); i += 256) {    // 2304 float4 pairs
        const int r = i / (P / 4), q = i % (P / 4);
        const int gy = gy0 + r, gx = gx0 + 4 * q;     // gx0 16-aligned: no straddle
        if (gy >= 0 && gy < HGT && gx >= 0 && gx < WID) {
            const size_t o = base + (size_t)gy * WID + gx;
            const float4 t = *reinterpret_cast<const float4*>(&Tin[o]);
            const float4 s = *reinterpret_cast<const float4*>(&sos[o]);
            // !(x>=0) catches negatives AND NaN
            bad |= (!(t.x >= 0.f)) | (!(t.y >= 0.f)) | (!(t.z >= 0.f)) | (!(t.w >= 0.f));
            bad |= (!(s.x >= 0.f)) | (!(s.y >= 0.f)) | (!(s.z >= 0.f)) | (!(s.w >= 0.f));
            mT = fmaxf(mT, fmaxf(fmaxf(t.x, t.y), fmaxf(t.z, t.w)));
            mS = fminf(mS, fminf(fminf(s.x, s.y), fminf(s.z, s.w)));
        }
    }
    #pragma unroll
    for (int off = 32; off > 0; off >>= 1) {
        mT = fmaxf(mT, __shfl_down(mT, off, 64));
        mS = fminf(mS, __shfl_down(mS, off, 64));
        bad |= __shfl_down(bad, off, 64);
    }
    const int wv = tid >> 6;
    if ((tid & 63) == 0) { redT[wv] = mT; redS[wv] = mS; redB[wv] = bad; }
    __syncthreads();
    if (tid == 0) {
        const float fT = fmaxf(fmaxf(redT[0], redT[1]), fmaxf(redT[2], redT[3]));
        const float fS = fminf(fminf(redS[0], redS[1]), fminf(redS[2], redS[3]));
        const unsigned fB = redB[0] | redB[1] | redB[2] | redB[3];
        unsigned dec = 0u;
        if (fB == 0u) {
            const float maxSlow = 1.0f / fS;
            float lb = log2f(fT);
            bool ok = true;
            #pragma unroll 1
            for (int l = 0; l < NLAY; ++l) {
                float ssum = 0.0f;
                #pragma unroll
                for (int k = 0; k < 9; ++k) {
                    const float w = swt[l * 9 + k];
                    ok &= (w >= 0.0f);
                    ssum += w;
                }
                lb += log2f(ssum * maxSlow);
            }
            if (ok && lb < -151.0f) dec = 1u;
        }
        decision = dec;
    }
    __syncthreads();

    if (decision != 0u) {
        // every output of this tile provably rounds to +0: stream zeros
        #pragma unroll
        for (int k = 0; k < 4; ++k) {
            const int i = tid + k * 256;              // 1024 float4s
            const int r = i >> 4, q = i & 15;
            *reinterpret_cast<float4*>(
                &Tout[base + (size_t)(gy0 + HALO + r) * WID + (gx0 + HALO + 4 * q)]) =
                make_float4(0.f, 0.f, 0.f, 0.f);
        }
        return;
    }

    // ---- fallback: full 16-layer fused stencil (tile data is L2-hot)
    for (int i = tid; i < LROWS * LSTR; i += 256) lds[i] = 0.0f;
    __syncthreads();
    for (int i = tid; i < P * P; i += 256) {
        const int r = i / P, c = i % P;
        const int gy = gy0 + r, gx = gx0 + c;
        float v = 0.0f;
        if (gy >= 0 && gy < HGT && gx >= 0 && gx < WID)
            v = Tin[base + (size_t)gy * WID + gx];
        lds[(r + 1) * LSTR + (c + 1)] = v;
    }

    const int tx = tid & 15, ty = tid >> 4;
    const int R0 = ty * CH, C0 = tx * CW;
    float slow[CH][CW];
    #pragma unroll
    for (int r = 0; r < CH; ++r) {
        #pragma unroll
        for (int j = 0; j < CW; ++j) {
            const int gy = gy0 + R0 + r, gx = gx0 + C0 + j;
            float sv = 1.0f;
            if (gy >= 0 && gy < HGT && gx >= 0 && gx < WID)
                sv = sos[base + (size_t)gy * WID + gx];
            slow[r][j] = 1.0f / sv;   // same single-division rounding as reference
        }
    }
    __syncthreads();

    float nw[CH][CW];
    #pragma unroll 1
    for (int it = 0; it < NLAY; ++it) {
        const float w00 = swt[it * 9 + 0], w01 = swt[it * 9 + 1], w02 = swt[it * 9 + 2];
        const float w10 = swt[it * 9 + 3], w11 = swt[it * 9 + 4], w12 = swt[it * 9 + 5];
        const float w20 = swt[it * 9 + 6], w21 = swt[it * 9 + 7], w22 = swt[it * 9 + 8];

        const bool uni = (w00 == w01) & (w01 == w02) & (w02 == w10) &
                         (w10 == w11) & (w11 == w12) & (w12 == w20) &
                         (w20 == w21) & (w21 == w22);

        float a[CW + 2], bb[CW + 2], cc[CW + 2];
        #pragma unroll
        for (int k = 0; k < CW + 2; ++k) a[k] = lds[R0 * LSTR + C0 + k];
        #pragma unroll
        for (int k = 0; k < CW + 2; ++k) bb[k] = lds[(R0 + 1) * LSTR + C0 + k];

        if (uni) {
            const float wu = w00;
            #pragma unroll
            for (int r = 0; r < CH; ++r) {
                #pragma unroll
                for (int k = 0; k < CW + 2; ++k) cc[k] = lds[(R0 + r + 2) * LSTR + C0 + k];
                float cs[CW + 2];
                #pragma unroll
                for (int k = 0; k < CW + 2; ++k) cs[k] = a[k] + bb[k] + cc[k];
                #pragma unroll
                for (int j = 0; j < CW; ++j) {
                    const float s9 = cs[j] + cs[j + 1] + cs[j + 2];
                    nw[r][j] = fminf(bb[j + 1], s9 * wu * slow[r][j]);
                }
                #pragma unroll
                for (int k = 0; k < CW + 2; ++k) { a[k] = bb[k]; bb[k] = cc[k]; }
            }
        } else {
            // exact general path (round-1-identical FMA chain)
            #pragma unroll
            for (int r = 0; r < CH; ++r) {
                #pragma unroll
                for (int k = 0; k < CW + 2; ++k) cc[k] = lds[(R0 + r + 2) * LSTR + C0 + k];
                #pragma unroll
                for (int j = 0; j < CW; ++j) {
                    float acc = a[j] * w00 + a[j + 1] * w01 + a[j + 2] * w02
                              + bb[j] * w10 + bb[j + 1] * w11 + bb[j + 2] * w12
                              + cc[j] * w20 + cc[j + 1] * w21 + cc[j + 2] * w22;
                    nw[r][j] = fminf(bb[j + 1], acc * slow[r][j]);
                }
                #pragma unroll
                for (int k = 0; k < CW + 2; ++k) { a[k] = bb[k]; bb[k] = cc[k]; }
            }
        }
        __syncthreads();
        #pragma unroll
        for (int r = 0; r < CH; ++r)
            #pragma unroll
            for (int j = 0; j < CW; ++j)
                lds[(R0 + r + 1) * LSTR + C0 + j + 1] = nw[r][j];
        __syncthreads();
    }

    // write valid inner TILE x TILE (float4, always fully in-image)
    #pragma unroll
    for (int k = 0; k < 4; ++k) {
        const int i = tid + k * 256;
        const int r = i >> 4, q = i & 15;
        const int o = (HALO + r + 1) * LSTR + HALO + 4 * q + 1;
        float4 v;
        v.x = lds[o]; v.y = lds[o + 1]; v.z = lds[o + 2]; v.w = lds[o + 3];
        *reinterpret_cast<float4*>(
            &Tout[base + (size_t)(gy0 + HALO + r) * WID + (gx0 + HALO + 4 * q)]) = v;
    }
}

extern "C" void kernel_launch(void* const* d_in, const int* in_sizes, int n_in,
                              void* d_out, int out_size, void* d_ws, size_t ws_size,
                              hipStream_t stream) {
    const float* T_init = (const float*)d_in[0];
    const float* sos    = (const float*)d_in[1];
    const float* wts    = (const float*)d_in[2];
    float* out = (float*)d_out;

    eik_all<<<dim3(2048), dim3(256), 0, stream>>>(T_init, sos, wts, out);
}